// Round 14
// baseline (1032.400 us; speedup 1.0000x reference)
//
#include <hip/hip_runtime.h>
#include <hip/hip_bf16.h>
#include <math.h>

using hbf = __hip_bfloat16;
typedef __bf16 bf16x8 __attribute__((ext_vector_type(8)));
typedef float f32x4 __attribute__((ext_vector_type(4)));

// within-16-lane rotate-reduce on the VALU (DPP row_ror) — no LDS traffic
__device__ inline float r16d(float v){
  int x;
  x = __builtin_bit_cast(int, v);
  v += __builtin_bit_cast(float, __builtin_amdgcn_mov_dpp(x, 0x121, 0xf, 0xf, true)); // ror:1
  x = __builtin_bit_cast(int, v);
  v += __builtin_bit_cast(float, __builtin_amdgcn_mov_dpp(x, 0x122, 0xf, 0xf, true)); // ror:2
  x = __builtin_bit_cast(int, v);
  v += __builtin_bit_cast(float, __builtin_amdgcn_mov_dpp(x, 0x124, 0xf, 0xf, true)); // ror:4
  x = __builtin_bit_cast(int, v);
  v += __builtin_bit_cast(float, __builtin_amdgcn_mov_dpp(x, 0x128, 0xf, 0xf, true)); // ror:8
  return v;
}
// 4 interleaved r16 reductions: DPP hazards overlap across independent chains
__device__ inline void r16d4(float& a, float& b, float& c, float& d){
#define R16STAGE(ctl) { \
  int xa=__builtin_bit_cast(int,a), xb=__builtin_bit_cast(int,b); \
  int xc=__builtin_bit_cast(int,c), xd=__builtin_bit_cast(int,d); \
  a += __builtin_bit_cast(float, __builtin_amdgcn_mov_dpp(xa, ctl, 0xf, 0xf, true)); \
  b += __builtin_bit_cast(float, __builtin_amdgcn_mov_dpp(xb, ctl, 0xf, 0xf, true)); \
  c += __builtin_bit_cast(float, __builtin_amdgcn_mov_dpp(xc, ctl, 0xf, 0xf, true)); \
  d += __builtin_bit_cast(float, __builtin_amdgcn_mov_dpp(xd, ctl, 0xf, 0xf, true)); }
  R16STAGE(0x121) R16STAGE(0x122) R16STAGE(0x124) R16STAGE(0x128)
#undef R16STAGE
}
__device__ inline float wred(float v){
  v = r16d(v);
  v += __shfl_xor(v, 16);
  v += __shfl_xor(v, 32);
  return v;
}
__device__ inline float fast_rcp(float x){
  float r; asm("v_rcp_f32 %0, %1" : "=v"(r) : "v"(x)); return r;
}
__device__ inline float d4(const float4& a, const float4& b){
  return a.x*b.x + a.y*b.y + a.z*b.z + a.w*b.w;
}

// ---------------- init: zero the two accumulators (ws is poisoned 0xAA once) ----
__global__ void k_init(float* scal){
  if (threadIdx.x < 2) scal[threadIdx.x] = 0.f;
}

// ------- fused distances/softmax/agg/vq-loss (phase A) + Gram MFMA (phase B) ----
// One block per batch; phase B re-reads this batch's X (602 KB) through L2.
__global__ __launch_bounds__(512) void k_dg(const float* __restrict__ x,
    const float* __restrict__ vqcb, const float* __restrict__ agcb,
    hbf* __restrict__ aggbf, float* __restrict__ scal, float* __restrict__ G){
  __shared__ __align__(16) char smem[43264];   // union: phase A 43,064 B / phase B 43,264 B
  __shared__ float sqA[7], sqV[7];
  const int tid = threadIdx.x, lane = tid & 63, wave = tid >> 6;
  const int b = blockIdx.x;
  const float* xb = x + (size_t)b*196*768;
  // =========================== phase A: dist ===========================
  {
    float* cA = (float*)smem;
    float* cV = cA + 5376;
    for (int i = tid; i < 5376; i += 512){ cA[i] = agcb[i]; cV[i] = vqcb[i]; }
    __syncthreads();
    {
      int grp = tid >> 4, l16 = tid & 15;
      if (grp < 14){
        const float* s = (grp < 7) ? &cA[grp*768] : &cV[(grp-7)*768];
        float acc = 0.f;
        for (int j = l16; j < 768; j += 16) acc += s[j]*s[j];
        acc = r16d(acc);
        if (l16 == 0){ if (grp < 7) sqA[grp] = acc; else sqV[grp-7] = acc; }
      }
    }
    __syncthreads();
    float sqAr[7], sqVr[7];
#pragma unroll
    for (int k = 0; k < 7; ++k){ sqAr[k] = sqA[k]; sqVr[k] = sqV[k]; }
    float4 aR[7][3];
#pragma unroll
    for (int k = 0; k < 7; ++k)
#pragma unroll
      for (int c = 0; c < 3; ++c) aR[k][c] = make_float4(0.f,0.f,0.f,0.f);
    float loss = 0.f;
    float4 cx0, cx1, cx2, nx0, nx1, nx2;
    { const float* p = xb + (size_t)wave*768 + (lane<<2);
      cx0 = *(const float4*)(p); cx1 = *(const float4*)(p+256); cx2 = *(const float4*)(p+512); }
    for (int it = 0; it < 25; ++it){
      const int n = it*8 + wave;
      const int nn = n + 8;
      if (nn < 196){
        const float* p = xb + (size_t)nn*768 + (lane<<2);
        nx0 = *(const float4*)(p); nx1 = *(const float4*)(p+256); nx2 = *(const float4*)(p+512);
      }
      if (n < 196){
        float xsq = d4(cx0,cx0)+d4(cx1,cx1)+d4(cx2,cx2);
        float dA[7], dV[7];
#pragma unroll
        for (int k = 0; k < 7; ++k){
          const float4* pa = (const float4*)&cA[k*768];
          const float4* pv = (const float4*)&cV[k*768];
          float4 a0 = pa[lane], a1 = pa[64+lane], a2 = pa[128+lane];
          float4 q0 = pv[lane], q1 = pv[64+lane], q2 = pv[128+lane];
          dA[k] = d4(cx0,a0)+d4(cx1,a1)+d4(cx2,a2);
          dV[k] = d4(cx0,q0)+d4(cx1,q1)+d4(cx2,q2);
        }
        xsq = wred(xsq);
#pragma unroll
        for (int k = 0; k < 7; ++k){ dA[k] = wred(dA[k]); dV[k] = wred(dV[k]); }
        float lg[7], mx = -1e30f;
#pragma unroll
        for (int k = 0; k < 7; ++k){ lg[k] = 2.f*dA[k] - sqAr[k]; mx = fmaxf(mx, lg[k]); }
        float pr[7], ssum = 0.f;
#pragma unroll
        for (int k = 0; k < 7; ++k){ pr[k] = expf(lg[k]-mx); ssum += pr[k]; }
        const float inv = 1.f/ssum;
        float mn = 1e30f;
#pragma unroll
        for (int k = 0; k < 7; ++k) mn = fminf(mn, sqVr[k] - 2.f*dV[k]);
        loss += xsq + mn;
#pragma unroll
        for (int k = 0; k < 7; ++k){
          const float w = pr[k]*inv;
          aR[k][0].x += w*cx0.x; aR[k][0].y += w*cx0.y; aR[k][0].z += w*cx0.z; aR[k][0].w += w*cx0.w;
          aR[k][1].x += w*cx1.x; aR[k][1].y += w*cx1.y; aR[k][1].z += w*cx1.z; aR[k][1].w += w*cx1.w;
          aR[k][2].x += w*cx2.x; aR[k][2].y += w*cx2.y; aR[k][2].z += w*cx2.z; aR[k][2].w += w*cx2.w;
        }
      }
      cx0 = nx0; cx1 = nx1; cx2 = nx2;
    }
    __syncthreads();
    for (int i = tid; i < 5376; i += 512) cA[i] = 0.f;
    __syncthreads();
    for (int w = 0; w < 8; ++w){
      if (wave == w){
#pragma unroll
        for (int k = 0; k < 7; ++k)
#pragma unroll
          for (int c = 0; c < 3; ++c){
            float* p = &cA[k*768 + c*256 + (lane<<2)];
            p[0] += aR[k][c].x; p[1] += aR[k][c].y; p[2] += aR[k][c].z; p[3] += aR[k][c].w;
          }
      }
      __syncthreads();
    }
    for (int i = tid; i < 5376; i += 512) aggbf[(size_t)b*5376 + i] = __float2bfloat16(cA[i]);
    if (lane == 0) atomicAdd(&scal[0], loss);
    __syncthreads();   // phase A fully done before smem is reused
  }
  // =========================== phase B: Gram ===========================
  {
    hbf* Xs = (hbf*)smem;                       // [208][104]
    const int l15 = lane & 15;
    const int fr0 = wave, fr1 = wave + 8;
    const bool f1 = (fr1 < 13);
    f32x4 acc0[13] = {};
    f32x4 acc1[13] = {};
    for (int kc = 0; kc < 8; ++kc){
      __syncthreads();
      for (int u = tid; u < 4992; u += 512){
        const int r = u / 24, c4 = u - r*24;
        ushort4 val;
        if (r < 196){
          float4 f = *(const float4*)(xb + (size_t)r*768 + kc*96 + c4*4);
          hbf t0 = __float2bfloat16(f.x), t1 = __float2bfloat16(f.y);
          hbf t2 = __float2bfloat16(f.z), t3 = __float2bfloat16(f.w);
          val.x = *(const unsigned short*)&t0; val.y = *(const unsigned short*)&t1;
          val.z = *(const unsigned short*)&t2; val.w = *(const unsigned short*)&t3;
        } else { val.x = 0; val.y = 0; val.z = 0; val.w = 0; }
        *(ushort4*)&Xs[r*104 + c4*4] = val;
      }
      __syncthreads();
#pragma unroll
      for (int kk = 0; kk < 3; ++kk){
        const int ko = kk*32 + (lane>>4)*8;
        bf16x8 a0 = *(const bf16x8*)&Xs[(fr0*16 + l15)*104 + ko];
        bf16x8 a1 = f1 ? *(const bf16x8*)&Xs[(fr1*16 + l15)*104 + ko] : a0;
#pragma unroll
        for (int fc = 0; fc < 13; ++fc){
          bf16x8 bb = *(const bf16x8*)&Xs[(fc*16 + l15)*104 + ko];
          acc0[fc] = __builtin_amdgcn_mfma_f32_16x16x32_bf16(a0, bb, acc0[fc], 0, 0, 0);
          if (f1) acc1[fc] = __builtin_amdgcn_mfma_f32_16x16x32_bf16(a1, bb, acc1[fc], 0, 0, 0);
        }
      }
    }
    const size_t gb = (size_t)b*38416;
    const int cr = (lane>>4)*4;
#pragma unroll
    for (int fc = 0; fc < 13; ++fc){
      const int gc = fc*16 + l15;
      if (gc < 196){
#pragma unroll
        for (int r = 0; r < 4; ++r){
          const int gr = fr0*16 + cr + r;
          if (gr < 196) G[gb + (size_t)gr*196 + gc] = acc0[fc][r];
        }
        if (f1){
#pragma unroll
          for (int r = 0; r < 4; ++r){
            const int gr = fr1*16 + cr + r;
            if (gr < 196) G[gb + (size_t)gr*196 + gc] = acc1[fc][r];
          }
        }
      }
    }
  }
}

// ---------------- eigen: blocked (rank-4 / two-reflector) Householder tridiag ----
// (unchanged from round 13 — verified)
#define ESTR 196
#define FOLD4v(FR, V0) { FR.x = (oc==0)? (V0) : FR.x; FR.y = (oc==1)? (V0) : FR.y; \
                         FR.z = (oc==2)? (V0) : FR.z; FR.w = (oc==3)? (V0) : FR.w; }
#define VH(COLC, BASE, OUT) { \
  const int col_ = (COLC) + jc4; \
  const float4 xv_ = *(const float4*)(rowk + col_); \
  float4 vp_; \
  if (col_ > (BASE)){ vp_ = xv_; } \
  else if (col_ + 3 <= (BASE)){ vp_ = make_float4(0.f,0.f,0.f,0.f); } \
  else { vp_.x = 0.f; \
         vp_.y = (col_+1 > (BASE)) ? xv_.y : 0.f; \
         vp_.z = (col_+2 > (BASE)) ? xv_.z : 0.f; \
         vp_.w = xv_.w; } \
  OUT = vp_; sig += vp_.x*vp_.x + vp_.y*vp_.y + vp_.z*vp_.z + vp_.w*vp_.w; }

__global__ __launch_bounds__(1024) void k_eigen(const float* __restrict__ G, float* __restrict__ scal){
  extern __shared__ float S[];
  float* A    = S;              // 38416 (+80 zeroed pad)
  float* ww1  = S + 38496;      // 256
  float* ww2  = S + 38752;      // 256
  float* dd   = S + 39008;      // 200
  float* ee   = S + 39208;      // 200
  float* e2   = S + 39408;      // 200
  float* red2 = S + 39608;      // 16
  float* red2b= S + 39624;      // 16
  const int n = 196;
  const int tid = threadIdx.x, lane = tid & 63, wave = tid >> 6;
  const int grp = lane >> 4, c16 = lane & 15;
  const int jc4 = c16 << 2;
  const int rbase = (wave << 2) + grp;
  const int b = blockIdx.x;
  {
    const float4* Gv = (const float4*)(G + (size_t)b*38416);
    float4* Av = (float4*)A;
    for (int u = tid; u < 9604; u += 1024) Av[u] = Gv[u];
    if (tid < 592) S[38416 + tid] = 0.f;   // pad(80)+ww1(256)+ww2(256)
  }
  __syncthreads();
  for (int k = 0; k <= 130; k += 2){
    const int base1 = k + 1, base2 = k + 2;
    const int m1 = n - 1 - k, m2 = n - 2 - k;
    const float* rowk  = &A[(size_t)k*ESTR];
    const float* rowk1 = &A[(size_t)base1*ESTR];
    if (tid == 0 && k > 0){
      ww1[k-1] = 0.f; ww1[k] = 0.f;
      ww2[k]   = 0.f; ww2[k+1] = 0.f;
    }
    const float x01 = rowk[base1];
    float4 v1f0, v1f1, v1f2, v1f3;
    float sig = 0.f;
    VH(0,   base1, v1f0)
    VH(64,  base1, v1f1)
    VH(128, base1, v1f2)
    { float4 vp = make_float4(0.f,0.f,0.f,0.f);
      if (c16 == 0){ vp = *(const float4*)(rowk + 192);
        sig += vp.x*vp.x + vp.y*vp.y + vp.z*vp.z + vp.w*vp.w; }
      v1f3 = vp; }
    sig = r16d(sig);
    float tau1 = 0.f, v01 = 0.f, alpha1 = x01;
    if (sig > 1e-20f){
      const float mu = sqrtf(x01*x01 + sig);
      alpha1 = (x01 > 0.f) ? -mu : mu;
      v01 = x01 - alpha1;
      tau1 = 2.f/(sig + v01*v01);
    }
    if (tid == 0) ee[k] = alpha1;
    if (c16 == ((base1 >> 2) & 15)){
      const int oc = base1 & 3, op = base1 >> 6;
      if (op == 0){ FOLD4v(v1f0, v01) } else if (op == 1){ FOLD4v(v1f1, v01) } else { FOLD4v(v1f2, v01) }
    }
    const int p0 = base1 >> 6;
    const int i0r = rbase, i1r = 64 + rbase, i2r = 128 + rbase, i3r = 192 + rbase;
    {
      float a0c = 0.f, a1c = 0.f, a2c = 0.f, a3c = 0.f;
#define MV1(IV, ACC) { \
      if ((IV) < m1){ \
        const float* Ar = &A[(size_t)(base1+(IV))*ESTR]; \
        if (0 >= p0) ACC += d4(*(const float4*)(Ar + jc4), v1f0); \
        if (1 >= p0) ACC += d4(*(const float4*)(Ar + 64 + jc4), v1f1); \
        if (2 >= p0) ACC += d4(*(const float4*)(Ar + 128 + jc4), v1f2); \
        if (c16 == 0) ACC += d4(*(const float4*)(Ar + 192), v1f3); } }
      MV1(i0r, a0c) MV1(i1r, a1c) MV1(i2r, a2c) MV1(i3r, a3c)
#undef MV1
      r16d4(a0c, a1c, a2c, a3c);
      float cp = 0.f;
#define CP1(IV, ACC) { \
      if ((IV) < m1){ \
        const float wr_ = tau1*(ACC); \
        const float vr_ = ((IV) == 0) ? v01 : rowk[base1+(IV)]; \
        cp += vr_*wr_; \
        if (c16 == 0) ww1[base1+(IV)] = wr_; } }
      CP1(i0r, a0c) CP1(i1r, a1c) CP1(i2r, a2c) CP1(i3r, a3c)
#undef CP1
      cp += __shfl_xor(cp, 16);
      cp += __shfl_xor(cp, 32);
      if (lane == 0) red2[wave] = cp;
    }
    __syncthreads();                               // B1
    float c21, w1head, tau2 = 0.f, v02 = 0.f;
    float4 w1f0, w1f1, w1f2, w1f3;
    float4 v2f0, v2f1, v2f2, v2f3;
    {
      const float4* r2 = (const float4*)red2;
      const float4 q0 = r2[0], q1 = r2[1], q2 = r2[2], q3 = r2[3];
      const float vtw = (q0.x+q0.y+q0.z+q0.w) + (q1.x+q1.y+q1.z+q1.w)
                      + (q2.x+q2.y+q2.z+q2.w) + (q3.x+q3.y+q3.z+q3.w);
      c21 = 0.5f*tau1*vtw;
      w1head = ww1[base1] - c21*v01;
      if (tid == 0) A[(size_t)base1*ESTR + base1] = rowk1[base1] - 2.f*v01*w1head; // dd[k+1]
#define W1F(COLC, VF, OUT) { \
      const float4 t4 = *(const float4*)(ww1 + (COLC) + jc4); \
      OUT.x = t4.x - c21*VF.x; OUT.y = t4.y - c21*VF.y; \
      OUT.z = t4.z - c21*VF.z; OUT.w = t4.w - c21*VF.w; }
      W1F(0,   v1f0, w1f0)
      W1F(64,  v1f1, w1f1)
      W1F(128, v1f2, w1f2)
      { float4 wp = make_float4(0.f,0.f,0.f,0.f);
        if (c16 == 0){ const float4 t4 = *(const float4*)(ww1 + 192);
          wp.x = t4.x - c21*v1f3.x; wp.y = t4.y - c21*v1f3.y;
          wp.z = t4.z - c21*v1f3.z; wp.w = t4.w - c21*v1f3.w; }
        w1f3 = wp; }
#undef W1F
      float sig2 = 0.f;
#define V2F(COLC, VF1, WF1, OUT) { \
      const int col_ = (COLC) + jc4; \
      const float4 r1_ = *(const float4*)(rowk1 + col_); \
      float4 rp_; \
      rp_.x = r1_.x - v01*WF1.x - w1head*VF1.x; \
      rp_.y = r1_.y - v01*WF1.y - w1head*VF1.y; \
      rp_.z = r1_.z - v01*WF1.z - w1head*VF1.z; \
      rp_.w = r1_.w - v01*WF1.w - w1head*VF1.w; \
      float4 vp_; \
      if (col_ > base2){ vp_ = rp_; } \
      else if (col_ + 3 <= base2){ vp_ = make_float4(0.f,0.f,0.f,0.f); } \
      else { vp_.x = 0.f; \
             vp_.y = (col_+1 > base2) ? rp_.y : 0.f; \
             vp_.z = (col_+2 > base2) ? rp_.z : 0.f; \
             vp_.w = rp_.w; } \
      OUT = vp_; sig2 += vp_.x*vp_.x + vp_.y*vp_.y + vp_.z*vp_.z + vp_.w*vp_.w; }
      V2F(0,   v1f0, w1f0, v2f0)
      V2F(64,  v1f1, w1f1, v2f1)
      V2F(128, v1f2, w1f2, v2f2)
      { float4 vp = make_float4(0.f,0.f,0.f,0.f);
        if (c16 == 0){ const float4 r1_ = *(const float4*)(rowk1 + 192);
          vp.x = r1_.x - v01*w1f3.x - w1head*v1f3.x;
          vp.y = r1_.y - v01*w1f3.y - w1head*v1f3.y;
          vp.z = r1_.z - v01*w1f3.z - w1head*v1f3.z;
          vp.w = r1_.w - v01*w1f3.w - w1head*v1f3.w;
          sig2 += vp.x*vp.x + vp.y*vp.y + vp.z*vp.z + vp.w*vp.w; }
        v2f3 = vp; }
#undef V2F
      sig2 = r16d(sig2);
      const float vb2 = rowk[base2];
      const float w1b2 = ww1[base2] - c21*vb2;
      const float x02 = rowk1[base2] - v01*w1b2 - w1head*vb2;
      float alpha2 = x02;
      if (sig2 > 1e-20f){
        const float mu = sqrtf(x02*x02 + sig2);
        alpha2 = (x02 > 0.f) ? -mu : mu;
        v02 = x02 - alpha2;
        tau2 = 2.f/(sig2 + v02*v02);
      }
      if (tid == 0) ee[base1] = alpha2;
      if (c16 == ((base2 >> 2) & 15)){
        const int oc = base2 & 3, op = base2 >> 6;
        if (op == 0){ FOLD4v(v2f0, v02) } else if (op == 1){ FOLD4v(v2f1, v02) } else { FOLD4v(v2f2, v02) }
      }
      float swv = d4(w1f0,v2f0) + d4(w1f1,v2f1) + d4(w1f2,v2f2) + d4(w1f3,v2f3);
      float svv = d4(v1f0,v2f0) + d4(v1f1,v2f1) + d4(v1f2,v2f2) + d4(v1f3,v2f3);
      swv = r16d(swv); svv = r16d(svv);
      float a0c = 0.f, a1c = 0.f, a2c = 0.f, a3c = 0.f;
#define MV2(IV, ACC) { \
      if ((IV) < m2){ \
        const float* Ar = &A[(size_t)(base2+(IV))*ESTR]; \
        if (0 >= p0) ACC += d4(*(const float4*)(Ar + jc4), v2f0); \
        if (1 >= p0) ACC += d4(*(const float4*)(Ar + 64 + jc4), v2f1); \
        if (2 >= p0) ACC += d4(*(const float4*)(Ar + 128 + jc4), v2f2); \
        if (c16 == 0) ACC += d4(*(const float4*)(Ar + 192), v2f3); } }
      MV2(i0r, a0c) MV2(i1r, a1c) MV2(i2r, a2c) MV2(i3r, a3c)
#undef MV2
      r16d4(a0c, a1c, a2c, a3c);
      float cp = 0.f;
#define CP2(IV, ACC) { \
      if ((IV) < m2){ \
        const int r_ = base2 + (IV); \
        const float v1r_ = rowk[r_]; \
        const float w1r_ = ww1[r_] - c21*v1r_; \
        const float u2_ = (ACC) - v1r_*swv - w1r_*svv; \
        const float w2r_ = tau2*u2_; \
        const float v2r_ = (r_ == base2) ? v02 : (rowk1[r_] - v01*w1r_ - w1head*v1r_); \
        cp += v2r_*w2r_; \
        if (c16 == 0) ww2[r_] = w2r_; } }
      CP2(i0r, a0c) CP2(i1r, a1c) CP2(i2r, a2c) CP2(i3r, a3c)
#undef CP2
      cp += __shfl_xor(cp, 16);
      cp += __shfl_xor(cp, 32);
      if (lane == 0) red2b[wave] = cp;
    }
    __syncthreads();                               // B2
    {
      const float4* r2 = (const float4*)red2b;
      const float4 q0 = r2[0], q1 = r2[1], q2 = r2[2], q3 = r2[3];
      const float vtw2 = (q0.x+q0.y+q0.z+q0.w) + (q1.x+q1.y+q1.z+q1.w)
                       + (q2.x+q2.y+q2.z+q2.w) + (q3.x+q3.y+q3.z+q3.w);
      const float c22 = 0.5f*tau2*vtw2;
      float4 w2f0, w2f1, w2f2, w2f3;
#define W2F(COLC, VF, OUT) { \
      const float4 t4 = *(const float4*)(ww2 + (COLC) + jc4); \
      OUT.x = t4.x - c22*VF.x; OUT.y = t4.y - c22*VF.y; \
      OUT.z = t4.z - c22*VF.z; OUT.w = t4.w - c22*VF.w; }
      W2F(0,   v2f0, w2f0)
      W2F(64,  v2f1, w2f1)
      W2F(128, v2f2, w2f2)
      { float4 wp = make_float4(0.f,0.f,0.f,0.f);
        if (c16 == 0){ const float4 t4 = *(const float4*)(ww2 + 192);
          wp.x = t4.x - c22*v2f3.x; wp.y = t4.y - c22*v2f3.y;
          wp.z = t4.z - c22*v2f3.z; wp.w = t4.w - c22*v2f3.w; }
        w2f3 = wp; }
#undef W2F
#define UPD(IV) { \
      if ((IV) < m2){ \
        const int r_ = base2 + (IV); \
        const float v1r = rowk[r_]; \
        const float w1r = ww1[r_] - c21*v1r; \
        const float v2r = (r_ == base2) ? v02 : (rowk1[r_] - v01*w1r - w1head*v1r); \
        const float w2r = ww2[r_] - c22*v2r; \
        float* Ar = &A[(size_t)r_*ESTR]; \
        if (0 >= p0){ float4 a = *(const float4*)(Ar + jc4); \
          a.x -= v1r*w1f0.x + w1r*v1f0.x + v2r*w2f0.x + w2r*v2f0.x; \
          a.y -= v1r*w1f0.y + w1r*v1f0.y + v2r*w2f0.y + w2r*v2f0.y; \
          a.z -= v1r*w1f0.z + w1r*v1f0.z + v2r*w2f0.z + w2r*v2f0.z; \
          a.w -= v1r*w1f0.w + w1r*v1f0.w + v2r*w2f0.w + w2r*v2f0.w; \
          *(float4*)(Ar + jc4) = a; } \
        if (1 >= p0){ float4 a = *(const float4*)(Ar + 64 + jc4); \
          a.x -= v1r*w1f1.x + w1r*v1f1.x + v2r*w2f1.x + w2r*v2f1.x; \
          a.y -= v1r*w1f1.y + w1r*v1f1.y + v2r*w2f1.y + w2r*v2f1.y; \
          a.z -= v1r*w1f1.z + w1r*v1f1.z + v2r*w2f1.z + w2r*v2f1.z; \
          a.w -= v1r*w1f1.w + w1r*v1f1.w + v2r*w2f1.w + w2r*v2f1.w; \
          *(float4*)(Ar + 64 + jc4) = a; } \
        if (2 >= p0){ float4 a = *(const float4*)(Ar + 128 + jc4); \
          a.x -= v1r*w1f2.x + w1r*v1f2.x + v2r*w2f2.x + w2r*v2f2.x; \
          a.y -= v1r*w1f2.y + w1r*v1f2.y + v2r*w2f2.y + w2r*v2f2.y; \
          a.z -= v1r*w1f2.z + w1r*v1f2.z + v2r*w2f2.z + w2r*v2f2.z; \
          a.w -= v1r*w1f2.w + w1r*v1f2.w + v2r*w2f2.w + w2r*v2f2.w; \
          *(float4*)(Ar + 128 + jc4) = a; } \
        if (c16 == 0){ float4 a = *(const float4*)(Ar + 192); \
          a.x -= v1r*w1f3.x + w1r*v1f3.x + v2r*w2f3.x + w2r*v2f3.x; \
          a.y -= v1r*w1f3.y + w1r*v1f3.y + v2r*w2f3.y + w2r*v2f3.y; \
          a.z -= v1r*w1f3.z + w1r*v1f3.z + v2r*w2f3.z + w2r*v2f3.z; \
          a.w -= v1r*w1f3.w + w1r*v1f3.w + v2r*w2f3.w + w2r*v2f3.w; \
          *(float4*)(Ar + 192) = a; } } }
      UPD(i0r) UPD(i1r) UPD(i2r) UPD(i3r)
#undef UPD
    }
    __syncthreads();                               // B3
  }
  // ================= tail steps: k = 132..193 (m = 63..2), wave 0 only =====
  if (wave == 0){
    float* ww = ww1;
    float vrT[16], wrT[16];
    for (int k = 132; k <= n-3; ++k){
      const int base = k + 1, m = n - 1 - k;
      const float* rowk = &A[(size_t)k*ESTR];
      const float x01 = rowk[base];
      if (lane == 0){ ww[k] = 0.f; ww[k-1] = 0.f; }
      float4 v4_2, v4_3;
      float sig = 0.f;
      { const int col_ = 128 + jc4;
        const float4 xv_ = *(const float4*)(rowk + col_);
        float4 vp_;
        if (col_ > base){ vp_ = xv_; }
        else if (col_ + 3 <= base){ vp_ = make_float4(0.f,0.f,0.f,0.f); }
        else { vp_.x = 0.f;
               vp_.y = (col_+1 > base) ? xv_.y : 0.f;
               vp_.z = (col_+2 > base) ? xv_.z : 0.f;
               vp_.w = xv_.w; }
        v4_2 = vp_; sig += vp_.x*vp_.x + vp_.y*vp_.y + vp_.z*vp_.z + vp_.w*vp_.w; }
      {
        float4 vp_ = make_float4(0.f,0.f,0.f,0.f);
        if (c16 == 0){
          const float4 xv_ = *(const float4*)(rowk + 192);
          if (192 > base){ vp_ = xv_; }
          else { vp_.x = 0.f;
                 vp_.y = (193 > base) ? xv_.y : 0.f;
                 vp_.z = (194 > base) ? xv_.z : 0.f;
                 vp_.w = xv_.w; }
        }
        v4_3 = vp_; sig += vp_.x*vp_.x + vp_.y*vp_.y + vp_.z*vp_.z + vp_.w*vp_.w;
      }
      sig = r16d(sig);
      float tau = 0.f, v0 = 0.f, alpha = x01;
      if (sig > 1e-20f){
        const float mu = sqrtf(x01*x01 + sig);
        alpha = (x01 > 0.f) ? -mu : mu;
        v0 = x01 - alpha;
        tau = 2.f/(sig + v0*v0);
      }
      if (lane == 0) ee[k] = alpha;
      if (c16 == ((base >> 2) & 15)){
        const int oc = base & 3;
        if ((base >> 6) == 2){ FOLD4v(v4_2, v0) } else { FOLD4v(v4_3, v0) }
      }
      if (tau != 0.f){
        float cpart = 0.f;
#pragma unroll
        for (int t = 0; t < 16; ++t){
          const int i_ = (t << 2) + grp;
          float vrv = 0.f, wrv = 0.f;
          if (i_ < m){
            const float* Ar = &A[(size_t)(base+i_)*ESTR];
            float acc = d4(*(const float4*)(Ar + 128 + jc4), v4_2);
            if (c16 == 0) acc += d4(*(const float4*)(Ar + 192), v4_3);
            acc = r16d(acc);
            wrv = tau*acc;
            vrv = (i_ == 0) ? v0 : rowk[base+i_];
            cpart += vrv*wrv;
            if (c16 == 0) ww[base+i_] = wrv;
          }
          vrT[t] = vrv; wrT[t] = wrv;
        }
        cpart += __shfl_xor(cpart, 16);
        cpart += __shfl_xor(cpart, 32);
        const float c2 = 0.5f*tau*cpart;
        __threadfence_block();
        float4 w4_2, w4_3 = make_float4(0.f,0.f,0.f,0.f);
        { const float4 t4 = *(const float4*)(ww + 128 + jc4);
          w4_2.x = t4.x - c2*v4_2.x; w4_2.y = t4.y - c2*v4_2.y; w4_2.z = t4.z - c2*v4_2.z; w4_2.w = t4.w - c2*v4_2.w; }
        if (c16 == 0){
          const float4 t4 = *(const float4*)(ww + 192);
          w4_3.x = t4.x - c2*v4_3.x; w4_3.y = t4.y - c2*v4_3.y; w4_3.z = t4.z - c2*v4_3.z; w4_3.w = t4.w - c2*v4_3.w; }
#pragma unroll
        for (int t = 0; t < 16; ++t){
          const int i_ = (t << 2) + grp;
          if (i_ < m){
            const float vi = vrT[t];
            const float wi = wrT[t] - c2*vi;
            float* Ar = &A[(size_t)(base+i_)*ESTR];
            float4 a = *(const float4*)(Ar + 128 + jc4);
            a.x -= vi*w4_2.x + wi*v4_2.x; a.y -= vi*w4_2.y + wi*v4_2.y;
            a.z -= vi*w4_2.z + wi*v4_2.z; a.w -= vi*w4_2.w + wi*v4_2.w;
            *(float4*)(Ar + 128 + jc4) = a;
            if (c16 == 0){
              float4 a3 = *(const float4*)(Ar + 192);
              a3.x -= vi*w4_3.x + wi*v4_3.x; a3.y -= vi*w4_3.y + wi*v4_3.y;
              a3.z -= vi*w4_3.z + wi*v4_3.z; a3.w -= vi*w4_3.w + wi*v4_3.w;
              *(float4*)(Ar + 192) = a3;
            }
          }
        }
        __threadfence_block();
      }
    }
  }
  __syncthreads();
  if (tid < n) dd[tid] = A[(size_t)tid*ESTR + tid];
  if (tid == 0) ee[n-2] = A[(size_t)(n-1)*ESTR + (n-2)];
  __syncthreads();
  if (tid < n-1) e2[tid] = ee[tid]*ee[tid];
  __syncthreads();
  float lo = 1e30f, hi = -1e30f;
  if (tid < n){
    const float rr = ((tid > 0) ? fabsf(ee[tid-1]) : 0.f) + ((tid < n-1) ? fabsf(ee[tid]) : 0.f);
    lo = dd[tid] - rr; hi = dd[tid] + rr;
  }
  {
    float l2 = lo, h2 = hi;
#pragma unroll
    for (int o = 32; o > 0; o >>= 1){
      l2 = fminf(l2, __shfl_xor(l2, o));
      h2 = fmaxf(h2, __shfl_xor(h2, o));
    }
    if (lane == 0){ ww1[wave] = l2; red2[wave] = h2; }
  }
  __syncthreads();
  float glo = ww1[0], ghi = red2[0];
#pragma unroll
  for (int w2 = 1; w2 < 16; ++w2){ glo = fminf(glo, ww1[w2]); ghi = fmaxf(ghi, red2[w2]); }
  __syncthreads();
  float sv = 0.f;
  if (tid < n){
    float lob = glo, hib = ghi;
    for (int it2 = 0; it2 < 18; ++it2){
      const float mid = 0.5f*(lob + hib);
      float q = dd[0] - mid;
      int cnt = (q < 0.f) ? 1 : 0;
      for (int i = 1; i < n; ++i){
        const float r = fast_rcp(q);
        q = (dd[i] - mid) - e2[i-1]*r;
        q = (fabsf(q) < 1e-6f) ? -1e-6f : q;
        cnt += (q < 0.f) ? 1 : 0;
      }
      if (cnt <= tid) lob = mid; else hib = mid;
    }
    sv = sqrtf(fmaxf(0.5f*(lob + hib), 0.f));
  }
  __syncthreads();
  if (tid < n) ww1[tid] = sv;
  __syncthreads();
  if (tid == 0){
    float tot = 0.f;
    for (int i = 0; i < n; ++i) tot += ww1[i];
    const float thr = 0.99f*tot;
    float cs = 0.f; int rank = 0;
    for (int i = n-1; i >= 0; --i){ cs += ww1[i]; rank += (cs <= thr) ? 1 : 0; }
    atomicAdd(&scal[1], (float)rank);
  }
}

// ---------------- transpose + f32->bf16 for weights ----------------------------
__global__ __launch_bounds__(256) void k_tr(const float* __restrict__ in, hbf* __restrict__ outp,
                                            int Rr, int Cc){
  __shared__ float t[32][33];
  const int tid = threadIdx.x;
  const int lc = tid & 31, lr = tid >> 5;
  const int c0 = blockIdx.x*32, r0 = blockIdx.y*32;
#pragma unroll
  for (int i = 0; i < 4; ++i)
    t[lr + i*8][lc] = in[(size_t)(r0 + lr + i*8)*Cc + c0 + lc];
  __syncthreads();
#pragma unroll
  for (int i = 0; i < 4; ++i)
    outp[(size_t)(c0 + lr + i*8)*Rr + r0 + lc] = __float2bfloat16(t[lc][lr + i*8]);
}

// ---------------- GEMM 128x128x64: A[M,K] * B^T[N,K], bf16 MFMA, 8 waves -------
template<int EPI>
__global__ __launch_bounds__(512) void k_gemm128(const hbf* __restrict__ Aa, const hbf* __restrict__ Bb,
    const float* __restrict__ bias, void* __restrict__ outp, int Ni, int Ki){
  __shared__ hbf As[128*72];
  __shared__ hbf Bs[128*72];
  const int tid = threadIdx.x, lane = tid & 63, wave = tid >> 6;
  const int row0 = blockIdx.y*128, col0 = blockIdx.x*128;
  const int m0 = (wave >> 2)*64, n0 = (wave & 3)*32;
  const int l15 = lane & 15, lk = (lane >> 4)*8;
  const int sr = tid >> 3, sc = (tid & 7)*8;
  f32x4 acc[4][2] = {};
  for (int kt = 0; kt < Ki; kt += 64){
    __syncthreads();
    *(uint4*)&As[sr*72 + sc]      = *(const uint4*)&Aa[(size_t)(row0+sr)*Ki + kt + sc];
    *(uint4*)&As[(sr+64)*72 + sc] = *(const uint4*)&Aa[(size_t)(row0+sr+64)*Ki + kt + sc];
    *(uint4*)&Bs[sr*72 + sc]      = *(const uint4*)&Bb[(size_t)(col0+sr)*Ki + kt + sc];
    *(uint4*)&Bs[(sr+64)*72 + sc] = *(const uint4*)&Bb[(size_t)(col0+sr+64)*Ki + kt + sc];
    __syncthreads();
#pragma unroll
    for (int kk = 0; kk < 2; ++kk){
      const int ko = kk*32 + lk;
      bf16x8 b0 = *(const bf16x8*)&Bs[(n0 + l15)*72 + ko];
      bf16x8 b1 = *(const bf16x8*)&Bs[(n0 + 16 + l15)*72 + ko];
#pragma unroll
      for (int mi = 0; mi < 4; ++mi){
        bf16x8 a = *(const bf16x8*)&As[(m0 + mi*16 + l15)*72 + ko];
        acc[mi][0] = __builtin_amdgcn_mfma_f32_16x16x32_bf16(a, b0, acc[mi][0], 0, 0, 0);
        acc[mi][1] = __builtin_amdgcn_mfma_f32_16x16x32_bf16(a, b1, acc[mi][1], 0, 0, 0);
      }
    }
  }
  const int cr = (lane >> 4)*4;
#pragma unroll
  for (int mi = 0; mi < 4; ++mi){
#pragma unroll
    for (int ni = 0; ni < 2; ++ni){
      const int gcol = col0 + n0 + ni*16 + l15;
#pragma unroll
      for (int r = 0; r < 4; ++r){
        const int grow = row0 + m0 + mi*16 + cr + r;
        float v = acc[mi][ni][r];
        if (EPI == 1){
          v += bias[gcol];
          v = 0.5f*v*(1.f + erff(v*0.70710678118654752f));
          ((hbf*)outp)[(size_t)grow*Ni + gcol] = __float2bfloat16(v);
        } else if (EPI == 2){
          v += bias[gcol];
          ((float*)outp)[(size_t)grow*Ni + gcol] = v;
        } else {
          ((float*)outp)[(size_t)grow*Ni + gcol] = v;
        }
      }
    }
  }
}

// ---------------- LayerNorm over 768, one wave per row --------------------------
__global__ __launch_bounds__(256) void k_ln(const float* __restrict__ h, const float* __restrict__ gam,
    const float* __restrict__ bet, hbf* __restrict__ hn){
  const int tid = threadIdx.x, lane = tid & 63, wave = tid >> 6;
  const int row = blockIdx.x*4 + wave;
  const float* hr = h + (size_t)row*768;
  const int off = lane*4;
  float4 v0 = *(const float4*)(hr + off);
  float4 v1 = *(const float4*)(hr + 256 + off);
  float4 v2 = *(const float4*)(hr + 512 + off);
  float s = v0.x+v0.y+v0.z+v0.w + v1.x+v1.y+v1.z+v1.w + v2.x+v2.y+v2.z+v2.w;
  s = wred(s);
  const float mu = s*(1.f/768.f);
  float q = 0.f;
  q += (v0.x-mu)*(v0.x-mu); q += (v0.y-mu)*(v0.y-mu); q += (v0.z-mu)*(v0.z-mu); q += (v0.w-mu)*(v0.w-mu);
  q += (v1.x-mu)*(v1.x-mu); q += (v1.y-mu)*(v1.y-mu); q += (v1.z-mu)*(v1.z-mu); q += (v1.w-mu)*(v1.w-mu);
  q += (v2.x-mu)*(v2.x-mu); q += (v2.y-mu)*(v2.y-mu); q += (v2.z-mu)*(v2.z-mu); q += (v2.w-mu)*(v2.w-mu);
  q = wred(q);
  const float rs = 1.f/sqrtf(q*(1.f/768.f) + 1e-5f);
  float4 g0 = *(const float4*)(gam + off), g1 = *(const float4*)(gam + 256 + off), g2 = *(const float4*)(gam + 512 + off);
  float4 t0 = *(const float4*)(bet + off), t1 = *(const float4*)(bet + 256 + off), t2 = *(const float4*)(bet + 512 + off);
  hbf* o = hn + (size_t)row*768;
  o[off+0] = __float2bfloat16((v0.x-mu)*rs*g0.x + t0.x);
  o[off+1] = __float2bfloat16((v0.y-mu)*rs*g0.y + t0.y);
  o[off+2] = __float2bfloat16((v0.z-mu)*rs*g0.z + t0.z);
  o[off+3] = __float2bfloat16((v0.w-mu)*rs*g0.w + t0.w);
  o[256+off+0] = __float2bfloat16((v1.x-mu)*rs*g1.x + t1.x);
  o[256+off+1] = __float2bfloat16((v1.y-mu)*rs*g1.y + t1.y);
  o[256+off+2] = __float2bfloat16((v1.z-mu)*rs*g1.z + t1.z);
  o[256+off+3] = __float2bfloat16((v1.w-mu)*rs*g1.w + t1.w);
  o[512+off+0] = __float2bfloat16((v2.x-mu)*rs*g2.x + t2.x);
  o[512+off+1] = __float2bfloat16((v2.y-mu)*rs*g2.y + t2.y);
  o[512+off+2] = __float2bfloat16((v2.z-mu)*rs*g2.z + t2.z);
  o[512+off+3] = __float2bfloat16((v2.w-mu)*rs*g2.w + t2.w);
}

// ---------------- head: normalize tok, grouped cosine logits, cls ---------------
__global__ __launch_bounds__(256) void k_head(const float* __restrict__ tok, const float* __restrict__ ce,
    const float* __restrict__ clsW, const float* __restrict__ clsb, const float* __restrict__ lgs,
    float* __restrict__ out){
  __shared__ float tkn[7*512];
  __shared__ float il[40];
  const int tid = threadIdx.x, lane = tid & 63, wave = tid >> 6;
  const int b = blockIdx.x;
  const float ls = lgs[0];
  for (int g = wave; g < 7; g += 4){
    const float* tr = tok + (size_t)(b*7 + g)*512;
    float4 u0 = *(const float4*)(tr + (lane<<3));
    float4 u1 = *(const float4*)(tr + (lane<<3) + 4);
    float s = d4(u0,u0) + d4(u1,u1);
    s = wred(s);
    const float inv = 1.f/sqrtf(s);
    float* dst = &tkn[g*512 + (lane<<3)];
    dst[0] = u0.x*inv; dst[1] = u0.y*inv; dst[2] = u0.z*inv; dst[3] = u0.w*inv;
    dst[4] = u1.x*inv; dst[5] = u1.y*inv; dst[6] = u1.z*inv; dst[7] = u1.w*inv;
  }
  __syncthreads();
  for (int c = wave; c < 34; c += 4){
    const int g = (c < 30) ? (c/5) : 6;
    const float* tp = &tkn[g*512 + (lane<<3)];
    const float* cp = ce + (size_t)c*512 + (lane<<3);
    float s = tp[0]*cp[0] + tp[1]*cp[1] + tp[2]*cp[2] + tp[3]*cp[3]
            + tp[4]*cp[4] + tp[5]*cp[5] + tp[6]*cp[6] + tp[7]*cp[7];
    s = wred(s);
    if (lane == 0){
      const float v = ls*s;
      il[c] = v;
      out[1792 + b*34 + c] = v;
    }
  }
  __syncthreads();
  if (tid < 7){
    float s = clsb[tid];
    for (int c = 0; c < 34; ++c) s += il[c]*clsW[c*7 + tid];
    out[b*7 + tid] = s;
  }
}

// ---------------- finalize scalars ----------------------------------------------
__global__ void k_fin(const float* __restrict__ scal, float* __restrict__ out){
  if (threadIdx.x == 0){
    out[10496] = 2.f*scal[0]/(float)(256*196*768);
    out[10497] = scal[1]*(1.f/256.f);
  }
}

extern "C" void kernel_launch(void* const* d_in, const int* in_sizes, int n_in,
                              void* d_out, int out_size, void* d_ws, size_t ws_size,
                              hipStream_t stream) {
  (void)in_sizes; (void)n_in; (void)out_size; (void)ws_size;
  const float* x    = (const float*)d_in[0];
  const float* vqcb = (const float*)d_in[1];
  const float* agcb = (const float*)d_in[2];
  const float* W1   = (const float*)d_in[3];
  const float* b1   = (const float*)d_in[4];
  const float* W2   = (const float*)d_in[5];
  const float* b2   = (const float*)d_in[6];
  const float* gam  = (const float*)d_in[7];
  const float* bet  = (const float*)d_in[8];
  const float* Wp   = (const float*)d_in[9];
  const float* ce   = (const float*)d_in[10];
  const float* clsW = (const float*)d_in[11];
  const float* clsb = (const float*)d_in[12];
  const float* lgs  = (const float*)d_in[13];
  float* out = (float*)d_out;
  char* w = (char*)d_ws;

  float* scal  = (float*)w;
  float* G     = (float*)(w + 256);
  hbf*   aggbf = (hbf*)(w + 39338240ULL);
  hbf*   W1t   = (hbf*)(w + 42090752ULL);
  hbf*   W2t   = (hbf*)(w + 46809344ULL);
  hbf*   Wpt   = (hbf*)(w + 51527936ULL);
  hbf*   h1    = (hbf*)(w + 256);
  float* hbuf  = (float*)(w + 256 + 16777216ULL);
  hbf*   hn    = (hbf*)(w + 256 + 25165824ULL);
  float* tok   = (float*)(w + 256 + 29360128ULL);

  k_init<<<dim3(1), dim3(64), 0, stream>>>(scal);
  k_dg<<<dim3(256), dim3(512), 0, stream>>>(x, vqcb, agcb, aggbf, scal, G);
  const int EIG_SMEM = 39640*4; // 158,560 B
  hipFuncSetAttribute((const void*)k_eigen, hipFuncAttributeMaxDynamicSharedMemorySize, EIG_SMEM);
  k_eigen<<<dim3(256), dim3(1024), EIG_SMEM, stream>>>(G, scal);
  k_tr<<<dim3(96,24), dim3(256), 0, stream>>>(W1, W1t, 768, 3072);
  k_tr<<<dim3(24,96), dim3(256), 0, stream>>>(W2, W2t, 3072, 768);
  k_tr<<<dim3(16,24), dim3(256), 0, stream>>>(Wp, Wpt, 768, 512);
  k_gemm128<1><<<dim3(24,14), dim3(512), 0, stream>>>(aggbf, W1t, b1, (void*)h1, 3072, 768);
  k_gemm128<2><<<dim3(6,14), dim3(512), 0, stream>>>(h1, W2t, b2, (void*)hbuf, 768, 3072);
  k_ln<<<dim3(448), dim3(256), 0, stream>>>(hbuf, gam, bet, hn);
  k_gemm128<3><<<dim3(4,14), dim3(512), 0, stream>>>(hn, Wpt, nullptr, (void*)tok, 512, 768);
  k_head<<<dim3(256), dim3(256), 0, stream>>>(tok, ce, clsW, clsb, lgs, out);
  k_fin<<<dim3(1), dim3(64), 0, stream>>>(scal, out);
}

// Round 15
// 1015.376 us; speedup vs baseline: 1.0168x; 1.0168x over previous
//
#include <hip/hip_runtime.h>
#include <hip/hip_bf16.h>
#include <math.h>

using hbf = __hip_bfloat16;
typedef __bf16 bf16x8 __attribute__((ext_vector_type(8)));
typedef float f32x4 __attribute__((ext_vector_type(4)));

// within-16-lane rotate-reduce on the VALU (DPP row_ror) — no LDS traffic
__device__ inline float r16d(float v){
  int x;
  x = __builtin_bit_cast(int, v);
  v += __builtin_bit_cast(float, __builtin_amdgcn_mov_dpp(x, 0x121, 0xf, 0xf, true)); // ror:1
  x = __builtin_bit_cast(int, v);
  v += __builtin_bit_cast(float, __builtin_amdgcn_mov_dpp(x, 0x122, 0xf, 0xf, true)); // ror:2
  x = __builtin_bit_cast(int, v);
  v += __builtin_bit_cast(float, __builtin_amdgcn_mov_dpp(x, 0x124, 0xf, 0xf, true)); // ror:4
  x = __builtin_bit_cast(int, v);
  v += __builtin_bit_cast(float, __builtin_amdgcn_mov_dpp(x, 0x128, 0xf, 0xf, true)); // ror:8
  return v;
}
// 4 interleaved r16 reductions: DPP hazards overlap across independent chains
__device__ inline void r16d4(float& a, float& b, float& c, float& d){
#define R16STAGE(ctl) { \
  int xa=__builtin_bit_cast(int,a), xb=__builtin_bit_cast(int,b); \
  int xc=__builtin_bit_cast(int,c), xd=__builtin_bit_cast(int,d); \
  a += __builtin_bit_cast(float, __builtin_amdgcn_mov_dpp(xa, ctl, 0xf, 0xf, true)); \
  b += __builtin_bit_cast(float, __builtin_amdgcn_mov_dpp(xb, ctl, 0xf, 0xf, true)); \
  c += __builtin_bit_cast(float, __builtin_amdgcn_mov_dpp(xc, ctl, 0xf, 0xf, true)); \
  d += __builtin_bit_cast(float, __builtin_amdgcn_mov_dpp(xd, ctl, 0xf, 0xf, true)); }
  R16STAGE(0x121) R16STAGE(0x122) R16STAGE(0x124) R16STAGE(0x128)
#undef R16STAGE
}
__device__ inline float wred(float v){
  v = r16d(v);
  v += __shfl_xor(v, 16);
  v += __shfl_xor(v, 32);
  return v;
}
__device__ inline float fast_rcp(float x){
  float r; asm("v_rcp_f32 %0, %1" : "=v"(r) : "v"(x)); return r;
}
__device__ inline float d4(const float4& a, const float4& b){
  return a.x*b.x + a.y*b.y + a.z*b.z + a.w*b.w;
}

// ---------------- init: zero the two accumulators (ws is poisoned 0xAA once) ----
__global__ void k_init(float* scal){
  if (threadIdx.x < 2) scal[threadIdx.x] = 0.f;
}

// ------- fused distances/softmax/agg/vq-loss (phase A) + Gram MFMA (phase B) ----
// One block per batch; phase B re-reads this batch's X (602 KB) through L2.
__global__ __launch_bounds__(512) void k_dg(const float* __restrict__ x,
    const float* __restrict__ vqcb, const float* __restrict__ agcb,
    hbf* __restrict__ aggbf, float* __restrict__ scal, float* __restrict__ G){
  __shared__ __align__(16) char smem[43264];   // union: phase A 43,064 B / phase B 43,264 B
  __shared__ float sqA[7], sqV[7];
  const int tid = threadIdx.x, lane = tid & 63, wave = tid >> 6;
  const int b = blockIdx.x;
  const float* xb = x + (size_t)b*196*768;
  // =========================== phase A: dist ===========================
  {
    float* cA = (float*)smem;
    float* cV = cA + 5376;
    for (int i = tid; i < 5376; i += 512){ cA[i] = agcb[i]; cV[i] = vqcb[i]; }
    __syncthreads();
    {
      int grp = tid >> 4, l16 = tid & 15;
      if (grp < 14){
        const float* s = (grp < 7) ? &cA[grp*768] : &cV[(grp-7)*768];
        float acc = 0.f;
        for (int j = l16; j < 768; j += 16) acc += s[j]*s[j];
        acc = r16d(acc);
        if (l16 == 0){ if (grp < 7) sqA[grp] = acc; else sqV[grp-7] = acc; }
      }
    }
    __syncthreads();
    float sqAr[7], sqVr[7];
#pragma unroll
    for (int k = 0; k < 7; ++k){ sqAr[k] = sqA[k]; sqVr[k] = sqV[k]; }
    float4 aR[7][3];
#pragma unroll
    for (int k = 0; k < 7; ++k)
#pragma unroll
      for (int c = 0; c < 3; ++c) aR[k][c] = make_float4(0.f,0.f,0.f,0.f);
    float loss = 0.f;
    float4 cx0, cx1, cx2, nx0, nx1, nx2;
    { const float* p = xb + (size_t)wave*768 + (lane<<2);
      cx0 = *(const float4*)(p); cx1 = *(const float4*)(p+256); cx2 = *(const float4*)(p+512); }
    for (int it = 0; it < 25; ++it){
      const int n = it*8 + wave;
      const int nn = n + 8;
      if (nn < 196){
        const float* p = xb + (size_t)nn*768 + (lane<<2);
        nx0 = *(const float4*)(p); nx1 = *(const float4*)(p+256); nx2 = *(const float4*)(p+512);
      }
      if (n < 196){
        float xsq = d4(cx0,cx0)+d4(cx1,cx1)+d4(cx2,cx2);
        float dA[7], dV[7];
#pragma unroll
        for (int k = 0; k < 7; ++k){
          const float4* pa = (const float4*)&cA[k*768];
          const float4* pv = (const float4*)&cV[k*768];
          float4 a0 = pa[lane], a1 = pa[64+lane], a2 = pa[128+lane];
          float4 q0 = pv[lane], q1 = pv[64+lane], q2 = pv[128+lane];
          dA[k] = d4(cx0,a0)+d4(cx1,a1)+d4(cx2,a2);
          dV[k] = d4(cx0,q0)+d4(cx1,q1)+d4(cx2,q2);
        }
        xsq = wred(xsq);
#pragma unroll
        for (int k = 0; k < 7; ++k){ dA[k] = wred(dA[k]); dV[k] = wred(dV[k]); }
        float lg[7], mx = -1e30f;
#pragma unroll
        for (int k = 0; k < 7; ++k){ lg[k] = 2.f*dA[k] - sqAr[k]; mx = fmaxf(mx, lg[k]); }
        float pr[7], ssum = 0.f;
#pragma unroll
        for (int k = 0; k < 7; ++k){ pr[k] = expf(lg[k]-mx); ssum += pr[k]; }
        const float inv = 1.f/ssum;
        float mn = 1e30f;
#pragma unroll
        for (int k = 0; k < 7; ++k) mn = fminf(mn, sqVr[k] - 2.f*dV[k]);
        loss += xsq + mn;
#pragma unroll
        for (int k = 0; k < 7; ++k){
          const float w = pr[k]*inv;
          aR[k][0].x += w*cx0.x; aR[k][0].y += w*cx0.y; aR[k][0].z += w*cx0.z; aR[k][0].w += w*cx0.w;
          aR[k][1].x += w*cx1.x; aR[k][1].y += w*cx1.y; aR[k][1].z += w*cx1.z; aR[k][1].w += w*cx1.w;
          aR[k][2].x += w*cx2.x; aR[k][2].y += w*cx2.y; aR[k][2].z += w*cx2.z; aR[k][2].w += w*cx2.w;
        }
      }
      cx0 = nx0; cx1 = nx1; cx2 = nx2;
    }
    __syncthreads();
    for (int i = tid; i < 5376; i += 512) cA[i] = 0.f;
    __syncthreads();
    for (int w = 0; w < 8; ++w){
      if (wave == w){
#pragma unroll
        for (int k = 0; k < 7; ++k)
#pragma unroll
          for (int c = 0; c < 3; ++c){
            float* p = &cA[k*768 + c*256 + (lane<<2)];
            p[0] += aR[k][c].x; p[1] += aR[k][c].y; p[2] += aR[k][c].z; p[3] += aR[k][c].w;
          }
      }
      __syncthreads();
    }
    for (int i = tid; i < 5376; i += 512) aggbf[(size_t)b*5376 + i] = __float2bfloat16(cA[i]);
    if (lane == 0) atomicAdd(&scal[0], loss);
    __syncthreads();   // phase A fully done before smem is reused
  }
  // =========================== phase B: Gram ===========================
  {
    hbf* Xs = (hbf*)smem;                       // [208][104]
    const int l15 = lane & 15;
    const int fr0 = wave, fr1 = wave + 8;
    const bool f1 = (fr1 < 13);
    f32x4 acc0[13] = {};
    f32x4 acc1[13] = {};
    for (int kc = 0; kc < 8; ++kc){
      __syncthreads();
      for (int u = tid; u < 4992; u += 512){
        const int r = u / 24, c4 = u - r*24;
        ushort4 val;
        if (r < 196){
          float4 f = *(const float4*)(xb + (size_t)r*768 + kc*96 + c4*4);
          hbf t0 = __float2bfloat16(f.x), t1 = __float2bfloat16(f.y);
          hbf t2 = __float2bfloat16(f.z), t3 = __float2bfloat16(f.w);
          val.x = *(const unsigned short*)&t0; val.y = *(const unsigned short*)&t1;
          val.z = *(const unsigned short*)&t2; val.w = *(const unsigned short*)&t3;
        } else { val.x = 0; val.y = 0; val.z = 0; val.w = 0; }
        *(ushort4*)&Xs[r*104 + c4*4] = val;
      }
      __syncthreads();
#pragma unroll
      for (int kk = 0; kk < 3; ++kk){
        const int ko = kk*32 + (lane>>4)*8;
        bf16x8 a0 = *(const bf16x8*)&Xs[(fr0*16 + l15)*104 + ko];
        bf16x8 a1 = f1 ? *(const bf16x8*)&Xs[(fr1*16 + l15)*104 + ko] : a0;
#pragma unroll
        for (int fc = 0; fc < 13; ++fc){
          bf16x8 bb = *(const bf16x8*)&Xs[(fc*16 + l15)*104 + ko];
          acc0[fc] = __builtin_amdgcn_mfma_f32_16x16x32_bf16(a0, bb, acc0[fc], 0, 0, 0);
          if (f1) acc1[fc] = __builtin_amdgcn_mfma_f32_16x16x32_bf16(a1, bb, acc1[fc], 0, 0, 0);
        }
      }
    }
    const size_t gb = (size_t)b*38416;
    const int cr = (lane>>4)*4;
#pragma unroll
    for (int fc = 0; fc < 13; ++fc){
      const int gc = fc*16 + l15;
      if (gc < 196){
#pragma unroll
        for (int r = 0; r < 4; ++r){
          const int gr = fr0*16 + cr + r;
          if (gr < 196) G[gb + (size_t)gr*196 + gc] = acc0[fc][r];
        }
        if (f1){
#pragma unroll
          for (int r = 0; r < 4; ++r){
            const int gr = fr1*16 + cr + r;
            if (gr < 196) G[gb + (size_t)gr*196 + gc] = acc1[fc][r];
          }
        }
      }
    }
  }
}

// ---------------- eigen: blocked (rank-4 / two-reflector) Householder tridiag ----
// (unchanged — verified at ~768 us)
#define ESTR 196
#define FOLD4v(FR, V0) { FR.x = (oc==0)? (V0) : FR.x; FR.y = (oc==1)? (V0) : FR.y; \
                         FR.z = (oc==2)? (V0) : FR.z; FR.w = (oc==3)? (V0) : FR.w; }
#define VH(COLC, BASE, OUT) { \
  const int col_ = (COLC) + jc4; \
  const float4 xv_ = *(const float4*)(rowk + col_); \
  float4 vp_; \
  if (col_ > (BASE)){ vp_ = xv_; } \
  else if (col_ + 3 <= (BASE)){ vp_ = make_float4(0.f,0.f,0.f,0.f); } \
  else { vp_.x = 0.f; \
         vp_.y = (col_+1 > (BASE)) ? xv_.y : 0.f; \
         vp_.z = (col_+2 > (BASE)) ? xv_.z : 0.f; \
         vp_.w = xv_.w; } \
  OUT = vp_; sig += vp_.x*vp_.x + vp_.y*vp_.y + vp_.z*vp_.z + vp_.w*vp_.w; }

__global__ __launch_bounds__(1024) void k_eigen(const float* __restrict__ G, float* __restrict__ scal){
  extern __shared__ float S[];
  float* A    = S;              // 38416 (+80 zeroed pad)
  float* ww1  = S + 38496;      // 256
  float* ww2  = S + 38752;      // 256
  float* dd   = S + 39008;      // 200
  float* ee   = S + 39208;      // 200
  float* e2   = S + 39408;      // 200
  float* red2 = S + 39608;      // 16
  float* red2b= S + 39624;      // 16
  const int n = 196;
  const int tid = threadIdx.x, lane = tid & 63, wave = tid >> 6;
  const int grp = lane >> 4, c16 = lane & 15;
  const int jc4 = c16 << 2;
  const int rbase = (wave << 2) + grp;
  const int b = blockIdx.x;
  {
    const float4* Gv = (const float4*)(G + (size_t)b*38416);
    float4* Av = (float4*)A;
    for (int u = tid; u < 9604; u += 1024) Av[u] = Gv[u];
    if (tid < 592) S[38416 + tid] = 0.f;   // pad(80)+ww1(256)+ww2(256)
  }
  __syncthreads();
  for (int k = 0; k <= 130; k += 2){
    const int base1 = k + 1, base2 = k + 2;
    const int m1 = n - 1 - k, m2 = n - 2 - k;
    const float* rowk  = &A[(size_t)k*ESTR];
    const float* rowk1 = &A[(size_t)base1*ESTR];
    if (tid == 0 && k > 0){
      ww1[k-1] = 0.f; ww1[k] = 0.f;
      ww2[k]   = 0.f; ww2[k+1] = 0.f;
    }
    const float x01 = rowk[base1];
    float4 v1f0, v1f1, v1f2, v1f3;
    float sig = 0.f;
    VH(0,   base1, v1f0)
    VH(64,  base1, v1f1)
    VH(128, base1, v1f2)
    { float4 vp = make_float4(0.f,0.f,0.f,0.f);
      if (c16 == 0){ vp = *(const float4*)(rowk + 192);
        sig += vp.x*vp.x + vp.y*vp.y + vp.z*vp.z + vp.w*vp.w; }
      v1f3 = vp; }
    sig = r16d(sig);
    float tau1 = 0.f, v01 = 0.f, alpha1 = x01;
    if (sig > 1e-20f){
      const float mu = sqrtf(x01*x01 + sig);
      alpha1 = (x01 > 0.f) ? -mu : mu;
      v01 = x01 - alpha1;
      tau1 = 2.f/(sig + v01*v01);
    }
    if (tid == 0) ee[k] = alpha1;
    if (c16 == ((base1 >> 2) & 15)){
      const int oc = base1 & 3, op = base1 >> 6;
      if (op == 0){ FOLD4v(v1f0, v01) } else if (op == 1){ FOLD4v(v1f1, v01) } else { FOLD4v(v1f2, v01) }
    }
    const int p0 = base1 >> 6;
    const int i0r = rbase, i1r = 64 + rbase, i2r = 128 + rbase, i3r = 192 + rbase;
    {
      float a0c = 0.f, a1c = 0.f, a2c = 0.f, a3c = 0.f;
#define MV1(IV, ACC) { \
      if ((IV) < m1){ \
        const float* Ar = &A[(size_t)(base1+(IV))*ESTR]; \
        if (0 >= p0) ACC += d4(*(const float4*)(Ar + jc4), v1f0); \
        if (1 >= p0) ACC += d4(*(const float4*)(Ar + 64 + jc4), v1f1); \
        if (2 >= p0) ACC += d4(*(const float4*)(Ar + 128 + jc4), v1f2); \
        if (c16 == 0) ACC += d4(*(const float4*)(Ar + 192), v1f3); } }
      MV1(i0r, a0c) MV1(i1r, a1c) MV1(i2r, a2c) MV1(i3r, a3c)
#undef MV1
      r16d4(a0c, a1c, a2c, a3c);
      float cp = 0.f;
#define CP1(IV, ACC) { \
      if ((IV) < m1){ \
        const float wr_ = tau1*(ACC); \
        const float vr_ = ((IV) == 0) ? v01 : rowk[base1+(IV)]; \
        cp += vr_*wr_; \
        if (c16 == 0) ww1[base1+(IV)] = wr_; } }
      CP1(i0r, a0c) CP1(i1r, a1c) CP1(i2r, a2c) CP1(i3r, a3c)
#undef CP1
      cp += __shfl_xor(cp, 16);
      cp += __shfl_xor(cp, 32);
      if (lane == 0) red2[wave] = cp;
    }
    __syncthreads();                               // B1
    float c21, w1head, tau2 = 0.f, v02 = 0.f;
    float4 w1f0, w1f1, w1f2, w1f3;
    float4 v2f0, v2f1, v2f2, v2f3;
    {
      const float4* r2 = (const float4*)red2;
      const float4 q0 = r2[0], q1 = r2[1], q2 = r2[2], q3 = r2[3];
      const float vtw = (q0.x+q0.y+q0.z+q0.w) + (q1.x+q1.y+q1.z+q1.w)
                      + (q2.x+q2.y+q2.z+q2.w) + (q3.x+q3.y+q3.z+q3.w);
      c21 = 0.5f*tau1*vtw;
      w1head = ww1[base1] - c21*v01;
      if (tid == 0) A[(size_t)base1*ESTR + base1] = rowk1[base1] - 2.f*v01*w1head; // dd[k+1]
#define W1F(COLC, VF, OUT) { \
      const float4 t4 = *(const float4*)(ww1 + (COLC) + jc4); \
      OUT.x = t4.x - c21*VF.x; OUT.y = t4.y - c21*VF.y; \
      OUT.z = t4.z - c21*VF.z; OUT.w = t4.w - c21*VF.w; }
      W1F(0,   v1f0, w1f0)
      W1F(64,  v1f1, w1f1)
      W1F(128, v1f2, w1f2)
      { float4 wp = make_float4(0.f,0.f,0.f,0.f);
        if (c16 == 0){ const float4 t4 = *(const float4*)(ww1 + 192);
          wp.x = t4.x - c21*v1f3.x; wp.y = t4.y - c21*v1f3.y;
          wp.z = t4.z - c21*v1f3.z; wp.w = t4.w - c21*v1f3.w; }
        w1f3 = wp; }
#undef W1F
      float sig2 = 0.f;
#define V2F(COLC, VF1, WF1, OUT) { \
      const int col_ = (COLC) + jc4; \
      const float4 r1_ = *(const float4*)(rowk1 + col_); \
      float4 rp_; \
      rp_.x = r1_.x - v01*WF1.x - w1head*VF1.x; \
      rp_.y = r1_.y - v01*WF1.y - w1head*VF1.y; \
      rp_.z = r1_.z - v01*WF1.z - w1head*VF1.z; \
      rp_.w = r1_.w - v01*WF1.w - w1head*VF1.w; \
      float4 vp_; \
      if (col_ > base2){ vp_ = rp_; } \
      else if (col_ + 3 <= base2){ vp_ = make_float4(0.f,0.f,0.f,0.f); } \
      else { vp_.x = 0.f; \
             vp_.y = (col_+1 > base2) ? rp_.y : 0.f; \
             vp_.z = (col_+2 > base2) ? rp_.z : 0.f; \
             vp_.w = rp_.w; } \
      OUT = vp_; sig2 += vp_.x*vp_.x + vp_.y*vp_.y + vp_.z*vp_.z + vp_.w*vp_.w; }
      V2F(0,   v1f0, w1f0, v2f0)
      V2F(64,  v1f1, w1f1, v2f1)
      V2F(128, v1f2, w1f2, v2f2)
      { float4 vp = make_float4(0.f,0.f,0.f,0.f);
        if (c16 == 0){ const float4 r1_ = *(const float4*)(rowk1 + 192);
          vp.x = r1_.x - v01*w1f3.x - w1head*v1f3.x;
          vp.y = r1_.y - v01*w1f3.y - w1head*v1f3.y;
          vp.z = r1_.z - v01*w1f3.z - w1head*v1f3.z;
          vp.w = r1_.w - v01*w1f3.w - w1head*v1f3.w;
          sig2 += vp.x*vp.x + vp.y*vp.y + vp.z*vp.z + vp.w*vp.w; }
        v2f3 = vp; }
#undef V2F
      sig2 = r16d(sig2);
      const float vb2 = rowk[base2];
      const float w1b2 = ww1[base2] - c21*vb2;
      const float x02 = rowk1[base2] - v01*w1b2 - w1head*vb2;
      float alpha2 = x02;
      if (sig2 > 1e-20f){
        const float mu = sqrtf(x02*x02 + sig2);
        alpha2 = (x02 > 0.f) ? -mu : mu;
        v02 = x02 - alpha2;
        tau2 = 2.f/(sig2 + v02*v02);
      }
      if (tid == 0) ee[base1] = alpha2;
      if (c16 == ((base2 >> 2) & 15)){
        const int oc = base2 & 3, op = base2 >> 6;
        if (op == 0){ FOLD4v(v2f0, v02) } else if (op == 1){ FOLD4v(v2f1, v02) } else { FOLD4v(v2f2, v02) }
      }
      float swv = d4(w1f0,v2f0) + d4(w1f1,v2f1) + d4(w1f2,v2f2) + d4(w1f3,v2f3);
      float svv = d4(v1f0,v2f0) + d4(v1f1,v2f1) + d4(v1f2,v2f2) + d4(v1f3,v2f3);
      swv = r16d(swv); svv = r16d(svv);
      float a0c = 0.f, a1c = 0.f, a2c = 0.f, a3c = 0.f;
#define MV2(IV, ACC) { \
      if ((IV) < m2){ \
        const float* Ar = &A[(size_t)(base2+(IV))*ESTR]; \
        if (0 >= p0) ACC += d4(*(const float4*)(Ar + jc4), v2f0); \
        if (1 >= p0) ACC += d4(*(const float4*)(Ar + 64 + jc4), v2f1); \
        if (2 >= p0) ACC += d4(*(const float4*)(Ar + 128 + jc4), v2f2); \
        if (c16 == 0) ACC += d4(*(const float4*)(Ar + 192), v2f3); } }
      MV2(i0r, a0c) MV2(i1r, a1c) MV2(i2r, a2c) MV2(i3r, a3c)
#undef MV2
      r16d4(a0c, a1c, a2c, a3c);
      float cp = 0.f;
#define CP2(IV, ACC) { \
      if ((IV) < m2){ \
        const int r_ = base2 + (IV); \
        const float v1r_ = rowk[r_]; \
        const float w1r_ = ww1[r_] - c21*v1r_; \
        const float u2_ = (ACC) - v1r_*swv - w1r_*svv; \
        const float w2r_ = tau2*u2_; \
        const float v2r_ = (r_ == base2) ? v02 : (rowk1[r_] - v01*w1r_ - w1head*v1r_); \
        cp += v2r_*w2r_; \
        if (c16 == 0) ww2[r_] = w2r_; } }
      CP2(i0r, a0c) CP2(i1r, a1c) CP2(i2r, a2c) CP2(i3r, a3c)
#undef CP2
      cp += __shfl_xor(cp, 16);
      cp += __shfl_xor(cp, 32);
      if (lane == 0) red2b[wave] = cp;
    }
    __syncthreads();                               // B2
    {
      const float4* r2 = (const float4*)red2b;
      const float4 q0 = r2[0], q1 = r2[1], q2 = r2[2], q3 = r2[3];
      const float vtw2 = (q0.x+q0.y+q0.z+q0.w) + (q1.x+q1.y+q1.z+q1.w)
                       + (q2.x+q2.y+q2.z+q2.w) + (q3.x+q3.y+q3.z+q3.w);
      const float c22 = 0.5f*tau2*vtw2;
      float4 w2f0, w2f1, w2f2, w2f3;
#define W2F(COLC, VF, OUT) { \
      const float4 t4 = *(const float4*)(ww2 + (COLC) + jc4); \
      OUT.x = t4.x - c22*VF.x; OUT.y = t4.y - c22*VF.y; \
      OUT.z = t4.z - c22*VF.z; OUT.w = t4.w - c22*VF.w; }
      W2F(0,   v2f0, w2f0)
      W2F(64,  v2f1, w2f1)
      W2F(128, v2f2, w2f2)
      { float4 wp = make_float4(0.f,0.f,0.f,0.f);
        if (c16 == 0){ const float4 t4 = *(const float4*)(ww2 + 192);
          wp.x = t4.x - c22*v2f3.x; wp.y = t4.y - c22*v2f3.y;
          wp.z = t4.z - c22*v2f3.z; wp.w = t4.w - c22*v2f3.w; }
        w2f3 = wp; }
#undef W2F
#define UPD(IV) { \
      if ((IV) < m2){ \
        const int r_ = base2 + (IV); \
        const float v1r = rowk[r_]; \
        const float w1r = ww1[r_] - c21*v1r; \
        const float v2r = (r_ == base2) ? v02 : (rowk1[r_] - v01*w1r - w1head*v1r); \
        const float w2r = ww2[r_] - c22*v2r; \
        float* Ar = &A[(size_t)r_*ESTR]; \
        if (0 >= p0){ float4 a = *(const float4*)(Ar + jc4); \
          a.x -= v1r*w1f0.x + w1r*v1f0.x + v2r*w2f0.x + w2r*v2f0.x; \
          a.y -= v1r*w1f0.y + w1r*v1f0.y + v2r*w2f0.y + w2r*v2f0.y; \
          a.z -= v1r*w1f0.z + w1r*v1f0.z + v2r*w2f0.z + w2r*v2f0.z; \
          a.w -= v1r*w1f0.w + w1r*v1f0.w + v2r*w2f0.w + w2r*v2f0.w; \
          *(float4*)(Ar + jc4) = a; } \
        if (1 >= p0){ float4 a = *(const float4*)(Ar + 64 + jc4); \
          a.x -= v1r*w1f1.x + w1r*v1f1.x + v2r*w2f1.x + w2r*v2f1.x; \
          a.y -= v1r*w1f1.y + w1r*v1f1.y + v2r*w2f1.y + w2r*v2f1.y; \
          a.z -= v1r*w1f1.z + w1r*v1f1.z + v2r*w2f1.z + w2r*v2f1.z; \
          a.w -= v1r*w1f1.w + w1r*v1f1.w + v2r*w2f1.w + w2r*v2f1.w; \
          *(float4*)(Ar + 64 + jc4) = a; } \
        if (2 >= p0){ float4 a = *(const float4*)(Ar + 128 + jc4); \
          a.x -= v1r*w1f2.x + w1r*v1f2.x + v2r*w2f2.x + w2r*v2f2.x; \
          a.y -= v1r*w1f2.y + w1r*v1f2.y + v2r*w2f2.y + w2r*v2f2.y; \
          a.z -= v1r*w1f2.z + w1r*v1f2.z + v2r*w2f2.z + w2r*v2f2.z; \
          a.w -= v1r*w1f2.w + w1r*v1f2.w + v2r*w2f2.w + w2r*v2f2.w; \
          *(float4*)(Ar + 128 + jc4) = a; } \
        if (c16 == 0){ float4 a = *(const float4*)(Ar + 192); \
          a.x -= v1r*w1f3.x + w1r*v1f3.x + v2r*w2f3.x + w2r*v2f3.x; \
          a.y -= v1r*w1f3.y + w1r*v1f3.y + v2r*w2f3.y + w2r*v2f3.y; \
          a.z -= v1r*w1f3.z + w1r*v1f3.z + v2r*w2f3.z + w2r*v2f3.z; \
          a.w -= v1r*w1f3.w + w1r*v1f3.w + v2r*w2f3.w + w2r*v2f3.w; \
          *(float4*)(Ar + 192) = a; } } }
      UPD(i0r) UPD(i1r) UPD(i2r) UPD(i3r)
#undef UPD
    }
    __syncthreads();                               // B3
  }
  // ================= tail steps: k = 132..193 (m = 63..2), wave 0 only =====
  if (wave == 0){
    float* ww = ww1;
    float vrT[16], wrT[16];
    for (int k = 132; k <= n-3; ++k){
      const int base = k + 1, m = n - 1 - k;
      const float* rowk = &A[(size_t)k*ESTR];
      const float x01 = rowk[base];
      if (lane == 0){ ww[k] = 0.f; ww[k-1] = 0.f; }
      float4 v4_2, v4_3;
      float sig = 0.f;
      { const int col_ = 128 + jc4;
        const float4 xv_ = *(const float4*)(rowk + col_);
        float4 vp_;
        if (col_ > base){ vp_ = xv_; }
        else if (col_ + 3 <= base){ vp_ = make_float4(0.f,0.f,0.f,0.f); }
        else { vp_.x = 0.f;
               vp_.y = (col_+1 > base) ? xv_.y : 0.f;
               vp_.z = (col_+2 > base) ? xv_.z : 0.f;
               vp_.w = xv_.w; }
        v4_2 = vp_; sig += vp_.x*vp_.x + vp_.y*vp_.y + vp_.z*vp_.z + vp_.w*vp_.w; }
      {
        float4 vp_ = make_float4(0.f,0.f,0.f,0.f);
        if (c16 == 0){
          const float4 xv_ = *(const float4*)(rowk + 192);
          if (192 > base){ vp_ = xv_; }
          else { vp_.x = 0.f;
                 vp_.y = (193 > base) ? xv_.y : 0.f;
                 vp_.z = (194 > base) ? xv_.z : 0.f;
                 vp_.w = xv_.w; }
        }
        v4_3 = vp_; sig += vp_.x*vp_.x + vp_.y*vp_.y + vp_.z*vp_.z + vp_.w*vp_.w;
      }
      sig = r16d(sig);
      float tau = 0.f, v0 = 0.f, alpha = x01;
      if (sig > 1e-20f){
        const float mu = sqrtf(x01*x01 + sig);
        alpha = (x01 > 0.f) ? -mu : mu;
        v0 = x01 - alpha;
        tau = 2.f/(sig + v0*v0);
      }
      if (lane == 0) ee[k] = alpha;
      if (c16 == ((base >> 2) & 15)){
        const int oc = base & 3;
        if ((base >> 6) == 2){ FOLD4v(v4_2, v0) } else { FOLD4v(v4_3, v0) }
      }
      if (tau != 0.f){
        float cpart = 0.f;
#pragma unroll
        for (int t = 0; t < 16; ++t){
          const int i_ = (t << 2) + grp;
          float vrv = 0.f, wrv = 0.f;
          if (i_ < m){
            const float* Ar = &A[(size_t)(base+i_)*ESTR];
            float acc = d4(*(const float4*)(Ar + 128 + jc4), v4_2);
            if (c16 == 0) acc += d4(*(const float4*)(Ar + 192), v4_3);
            acc = r16d(acc);
            wrv = tau*acc;
            vrv = (i_ == 0) ? v0 : rowk[base+i_];
            cpart += vrv*wrv;
            if (c16 == 0) ww[base+i_] = wrv;
          }
          vrT[t] = vrv; wrT[t] = wrv;
        }
        cpart += __shfl_xor(cpart, 16);
        cpart += __shfl_xor(cpart, 32);
        const float c2 = 0.5f*tau*cpart;
        __threadfence_block();
        float4 w4_2, w4_3 = make_float4(0.f,0.f,0.f,0.f);
        { const float4 t4 = *(const float4*)(ww + 128 + jc4);
          w4_2.x = t4.x - c2*v4_2.x; w4_2.y = t4.y - c2*v4_2.y; w4_2.z = t4.z - c2*v4_2.z; w4_2.w = t4.w - c2*v4_2.w; }
        if (c16 == 0){
          const float4 t4 = *(const float4*)(ww + 192);
          w4_3.x = t4.x - c2*v4_3.x; w4_3.y = t4.y - c2*v4_3.y; w4_3.z = t4.z - c2*v4_3.z; w4_3.w = t4.w - c2*v4_3.w; }
#pragma unroll
        for (int t = 0; t < 16; ++t){
          const int i_ = (t << 2) + grp;
          if (i_ < m){
            const float vi = vrT[t];
            const float wi = wrT[t] - c2*vi;
            float* Ar = &A[(size_t)(base+i_)*ESTR];
            float4 a = *(const float4*)(Ar + 128 + jc4);
            a.x -= vi*w4_2.x + wi*v4_2.x; a.y -= vi*w4_2.y + wi*v4_2.y;
            a.z -= vi*w4_2.z + wi*v4_2.z; a.w -= vi*w4_2.w + wi*v4_2.w;
            *(float4*)(Ar + 128 + jc4) = a;
            if (c16 == 0){
              float4 a3 = *(const float4*)(Ar + 192);
              a3.x -= vi*w4_3.x + wi*v4_3.x; a3.y -= vi*w4_3.y + wi*v4_3.y;
              a3.z -= vi*w4_3.z + wi*v4_3.z; a3.w -= vi*w4_3.w + wi*v4_3.w;
              *(float4*)(Ar + 192) = a3;
            }
          }
        }
        __threadfence_block();
      }
    }
  }
  __syncthreads();
  if (tid < n) dd[tid] = A[(size_t)tid*ESTR + tid];
  if (tid == 0) ee[n-2] = A[(size_t)(n-1)*ESTR + (n-2)];
  __syncthreads();
  if (tid < n-1) e2[tid] = ee[tid]*ee[tid];
  __syncthreads();
  float lo = 1e30f, hi = -1e30f;
  if (tid < n){
    const float rr = ((tid > 0) ? fabsf(ee[tid-1]) : 0.f) + ((tid < n-1) ? fabsf(ee[tid]) : 0.f);
    lo = dd[tid] - rr; hi = dd[tid] + rr;
  }
  {
    float l2 = lo, h2 = hi;
#pragma unroll
    for (int o = 32; o > 0; o >>= 1){
      l2 = fminf(l2, __shfl_xor(l2, o));
      h2 = fmaxf(h2, __shfl_xor(h2, o));
    }
    if (lane == 0){ ww1[wave] = l2; red2[wave] = h2; }
  }
  __syncthreads();
  float glo = ww1[0], ghi = red2[0];
#pragma unroll
  for (int w2 = 1; w2 < 16; ++w2){ glo = fminf(glo, ww1[w2]); ghi = fmaxf(ghi, red2[w2]); }
  __syncthreads();
  float sv = 0.f;
  if (tid < n){
    float lob = glo, hib = ghi;
    for (int it2 = 0; it2 < 18; ++it2){
      const float mid = 0.5f*(lob + hib);
      float q = dd[0] - mid;
      int cnt = (q < 0.f) ? 1 : 0;
      for (int i = 1; i < n; ++i){
        const float r = fast_rcp(q);
        q = (dd[i] - mid) - e2[i-1]*r;
        q = (fabsf(q) < 1e-6f) ? -1e-6f : q;
        cnt += (q < 0.f) ? 1 : 0;
      }
      if (cnt <= tid) lob = mid; else hib = mid;
    }
    sv = sqrtf(fmaxf(0.5f*(lob + hib), 0.f));
  }
  __syncthreads();
  if (tid < n) ww1[tid] = sv;
  __syncthreads();
  if (tid == 0){
    float tot = 0.f;
    for (int i = 0; i < n; ++i) tot += ww1[i];
    const float thr = 0.99f*tot;
    float cs = 0.f; int rank = 0;
    for (int i = n-1; i >= 0; --i){ cs += ww1[i]; rank += (cs <= thr) ? 1 : 0; }
    atomicAdd(&scal[1], (float)rank);
  }
}

// ---------------- transpose + f32->bf16 for weights ----------------------------
__global__ __launch_bounds__(256) void k_tr(const float* __restrict__ in, hbf* __restrict__ outp,
                                            int Rr, int Cc){
  __shared__ float t[32][33];
  const int tid = threadIdx.x;
  const int lc = tid & 31, lr = tid >> 5;
  const int c0 = blockIdx.x*32, r0 = blockIdx.y*32;
#pragma unroll
  for (int i = 0; i < 4; ++i)
    t[lr + i*8][lc] = in[(size_t)(r0 + lr + i*8)*Cc + c0 + lc];
  __syncthreads();
#pragma unroll
  for (int i = 0; i < 4; ++i)
    outp[(size_t)(c0 + lr + i*8)*Rr + r0 + lc] = __float2bfloat16(t[lc][lr + i*8]);
}

// ---------------- GEMM 128x128x64: A[M,K] * B^T[N,K], bf16 MFMA, 8 waves -------
template<int EPI>
__global__ __launch_bounds__(512) void k_gemm128(const hbf* __restrict__ Aa, const hbf* __restrict__ Bb,
    const float* __restrict__ bias, void* __restrict__ outp, int Ni, int Ki){
  __shared__ hbf As[128*72];
  __shared__ hbf Bs[128*72];
  const int tid = threadIdx.x, lane = tid & 63, wave = tid >> 6;
  const int row0 = blockIdx.y*128, col0 = blockIdx.x*128;
  const int m0 = (wave >> 2)*64, n0 = (wave & 3)*32;
  const int l15 = lane & 15, lk = (lane >> 4)*8;
  const int sr = tid >> 3, sc = (tid & 7)*8;
  f32x4 acc[4][2] = {};
  for (int kt = 0; kt < Ki; kt += 64){
    __syncthreads();
    *(uint4*)&As[sr*72 + sc]      = *(const uint4*)&Aa[(size_t)(row0+sr)*Ki + kt + sc];
    *(uint4*)&As[(sr+64)*72 + sc] = *(const uint4*)&Aa[(size_t)(row0+sr+64)*Ki + kt + sc];
    *(uint4*)&Bs[sr*72 + sc]      = *(const uint4*)&Bb[(size_t)(col0+sr)*Ki + kt + sc];
    *(uint4*)&Bs[(sr+64)*72 + sc] = *(const uint4*)&Bb[(size_t)(col0+sr+64)*Ki + kt + sc];
    __syncthreads();
#pragma unroll
    for (int kk = 0; kk < 2; ++kk){
      const int ko = kk*32 + lk;
      bf16x8 b0 = *(const bf16x8*)&Bs[(n0 + l15)*72 + ko];
      bf16x8 b1 = *(const bf16x8*)&Bs[(n0 + 16 + l15)*72 + ko];
#pragma unroll
      for (int mi = 0; mi < 4; ++mi){
        bf16x8 a = *(const bf16x8*)&As[(m0 + mi*16 + l15)*72 + ko];
        acc[mi][0] = __builtin_amdgcn_mfma_f32_16x16x32_bf16(a, b0, acc[mi][0], 0, 0, 0);
        acc[mi][1] = __builtin_amdgcn_mfma_f32_16x16x32_bf16(a, b1, acc[mi][1], 0, 0, 0);
      }
    }
  }
  const int cr = (lane >> 4)*4;
#pragma unroll
  for (int mi = 0; mi < 4; ++mi){
#pragma unroll
    for (int ni = 0; ni < 2; ++ni){
      const int gcol = col0 + n0 + ni*16 + l15;
#pragma unroll
      for (int r = 0; r < 4; ++r){
        const int grow = row0 + m0 + mi*16 + cr + r;
        float v = acc[mi][ni][r];
        if (EPI == 1){
          v += bias[gcol];
          v = 0.5f*v*(1.f + erff(v*0.70710678118654752f));
          ((hbf*)outp)[(size_t)grow*Ni + gcol] = __float2bfloat16(v);
        } else if (EPI == 2){
          v += bias[gcol];
          ((float*)outp)[(size_t)grow*Ni + gcol] = v;
        } else {
          ((float*)outp)[(size_t)grow*Ni + gcol] = v;
        }
      }
    }
  }
}

// ---------------- GEMM: A[M,K] * B^T[N,K], bf16 MFMA 16x16x32, 64x64 tiles ------
template<int EPI>
__global__ __launch_bounds__(256) void k_gemm(const hbf* __restrict__ Aa, const hbf* __restrict__ Bb,
    const float* __restrict__ bias, void* __restrict__ outp, int Mi, int Ni, int Ki){
  __shared__ hbf As[64*72];
  __shared__ hbf Bs[64*72];
  const int tid = threadIdx.x, lane = tid & 63, wave = tid >> 6;
  const int row0 = blockIdx.y*64, col0 = blockIdx.x*64;
  const int m0 = (wave >> 1)*32, n0 = (wave & 1)*32;
  const int l15 = lane & 15, lk = (lane >> 4)*8;
  const int sr = tid >> 3, sc = (tid & 7)*8;
  f32x4 acc00 = {}, acc01 = {}, acc10 = {}, acc11 = {};
  for (int kt = 0; kt < Ki; kt += 64){
    __syncthreads();
    *(uint4*)&As[sr*72 + sc]        = *(const uint4*)&Aa[(size_t)(row0+sr)*Ki + kt + sc];
    *(uint4*)&As[(sr+32)*72 + sc]   = *(const uint4*)&Aa[(size_t)(row0+sr+32)*Ki + kt + sc];
    *(uint4*)&Bs[sr*72 + sc]        = *(const uint4*)&Bb[(size_t)(col0+sr)*Ki + kt + sc];
    *(uint4*)&Bs[(sr+32)*72 + sc]   = *(const uint4*)&Bb[(size_t)(col0+sr+32)*Ki + kt + sc];
    __syncthreads();
#pragma unroll
    for (int kk = 0; kk < 2; ++kk){
      const int ko = kk*32 + lk;
      bf16x8 a0 = *(const bf16x8*)&As[(m0 + l15)*72 + ko];
      bf16x8 a1 = *(const bf16x8*)&As[(m0 + 16 + l15)*72 + ko];
      bf16x8 b0 = *(const bf16x8*)&Bs[(n0 + l15)*72 + ko];
      bf16x8 b1 = *(const bf16x8*)&Bs[(n0 + 16 + l15)*72 + ko];
      acc00 = __builtin_amdgcn_mfma_f32_16x16x32_bf16(a0, b0, acc00, 0, 0, 0);
      acc01 = __builtin_amdgcn_mfma_f32_16x16x32_bf16(a0, b1, acc01, 0, 0, 0);
      acc10 = __builtin_amdgcn_mfma_f32_16x16x32_bf16(a1, b0, acc10, 0, 0, 0);
      acc11 = __builtin_amdgcn_mfma_f32_16x16x32_bf16(a1, b1, acc11, 0, 0, 0);
    }
  }
  const int cr = (lane >> 4)*4;
#pragma unroll
  for (int i = 0; i < 2; ++i){
#pragma unroll
    for (int j = 0; j < 2; ++j){
      f32x4 av = (i == 0) ? ((j == 0) ? acc00 : acc01) : ((j == 0) ? acc10 : acc11);
      const int gcol = col0 + n0 + j*16 + l15;
#pragma unroll
      for (int r = 0; r < 4; ++r){
        const int grow = row0 + m0 + i*16 + cr + r;
        float v = av[r];
        if (EPI == 1){
          v += bias[gcol];
          v = 0.5f*v*(1.f + erff(v*0.70710678118654752f));
          ((hbf*)outp)[(size_t)grow*Ni + gcol] = __float2bfloat16(v);
        } else if (EPI == 2){
          v += bias[gcol];
          ((float*)outp)[(size_t)grow*Ni + gcol] = v;
        } else {
          ((float*)outp)[(size_t)grow*Ni + gcol] = v;
        }
      }
    }
  }
}

// ---------------- LayerNorm over 768, one wave per row --------------------------
__global__ __launch_bounds__(256) void k_ln(const float* __restrict__ h, const float* __restrict__ gam,
    const float* __restrict__ bet, hbf* __restrict__ hn){
  const int tid = threadIdx.x, lane = tid & 63, wave = tid >> 6;
  const int row = blockIdx.x*4 + wave;
  const float* hr = h + (size_t)row*768;
  const int off = lane*4;
  float4 v0 = *(const float4*)(hr + off);
  float4 v1 = *(const float4*)(hr + 256 + off);
  float4 v2 = *(const float4*)(hr + 512 + off);
  float s = v0.x+v0.y+v0.z+v0.w + v1.x+v1.y+v1.z+v1.w + v2.x+v2.y+v2.z+v2.w;
  s = wred(s);
  const float mu = s*(1.f/768.f);
  float q = 0.f;
  q += (v0.x-mu)*(v0.x-mu); q += (v0.y-mu)*(v0.y-mu); q += (v0.z-mu)*(v0.z-mu); q += (v0.w-mu)*(v0.w-mu);
  q += (v1.x-mu)*(v1.x-mu); q += (v1.y-mu)*(v1.y-mu); q += (v1.z-mu)*(v1.z-mu); q += (v1.w-mu)*(v1.w-mu);
  q += (v2.x-mu)*(v2.x-mu); q += (v2.y-mu)*(v2.y-mu); q += (v2.z-mu)*(v2.z-mu); q += (v2.w-mu)*(v2.w-mu);
  q = wred(q);
  const float rs = 1.f/sqrtf(q*(1.f/768.f) + 1e-5f);
  float4 g0 = *(const float4*)(gam + off), g1 = *(const float4*)(gam + 256 + off), g2 = *(const float4*)(gam + 512 + off);
  float4 t0 = *(const float4*)(bet + off), t1 = *(const float4*)(bet + 256 + off), t2 = *(const float4*)(bet + 512 + off);
  hbf* o = hn + (size_t)row*768;
  o[off+0] = __float2bfloat16((v0.x-mu)*rs*g0.x + t0.x);
  o[off+1] = __float2bfloat16((v0.y-mu)*rs*g0.y + t0.y);
  o[off+2] = __float2bfloat16((v0.z-mu)*rs*g0.z + t0.z);
  o[off+3] = __float2bfloat16((v0.w-mu)*rs*g0.w + t0.w);
  o[256+off+0] = __float2bfloat16((v1.x-mu)*rs*g1.x + t1.x);
  o[256+off+1] = __float2bfloat16((v1.y-mu)*rs*g1.y + t1.y);
  o[256+off+2] = __float2bfloat16((v1.z-mu)*rs*g1.z + t1.z);
  o[256+off+3] = __float2bfloat16((v1.w-mu)*rs*g1.w + t1.w);
  o[512+off+0] = __float2bfloat16((v2.x-mu)*rs*g2.x + t2.x);
  o[512+off+1] = __float2bfloat16((v2.y-mu)*rs*g2.y + t2.y);
  o[512+off+2] = __float2bfloat16((v2.z-mu)*rs*g2.z + t2.z);
  o[512+off+3] = __float2bfloat16((v2.w-mu)*rs*g2.w + t2.w);
}

// ---------------- head: normalize tok, grouped cosine logits, cls ---------------
__global__ __launch_bounds__(256) void k_head(const float* __restrict__ tok, const float* __restrict__ ce,
    const float* __restrict__ clsW, const float* __restrict__ clsb, const float* __restrict__ lgs,
    float* __restrict__ out){
  __shared__ float tkn[7*512];
  __shared__ float il[40];
  const int tid = threadIdx.x, lane = tid & 63, wave = tid >> 6;
  const int b = blockIdx.x;
  const float ls = lgs[0];
  for (int g = wave; g < 7; g += 4){
    const float* tr = tok + (size_t)(b*7 + g)*512;
    float4 u0 = *(const float4*)(tr + (lane<<3));
    float4 u1 = *(const float4*)(tr + (lane<<3) + 4);
    float s = d4(u0,u0) + d4(u1,u1);
    s = wred(s);
    const float inv = 1.f/sqrtf(s);
    float* dst = &tkn[g*512 + (lane<<3)];
    dst[0] = u0.x*inv; dst[1] = u0.y*inv; dst[2] = u0.z*inv; dst[3] = u0.w*inv;
    dst[4] = u1.x*inv; dst[5] = u1.y*inv; dst[6] = u1.z*inv; dst[7] = u1.w*inv;
  }
  __syncthreads();
  for (int c = wave; c < 34; c += 4){
    const int g = (c < 30) ? (c/5) : 6;
    const float* tp = &tkn[g*512 + (lane<<3)];
    const float* cp = ce + (size_t)c*512 + (lane<<3);
    float s = tp[0]*cp[0] + tp[1]*cp[1] + tp[2]*cp[2] + tp[3]*cp[3]
            + tp[4]*cp[4] + tp[5]*cp[5] + tp[6]*cp[6] + tp[7]*cp[7];
    s = wred(s);
    if (lane == 0){
      const float v = ls*s;
      il[c] = v;
      out[1792 + b*34 + c] = v;
    }
  }
  __syncthreads();
  if (tid < 7){
    float s = clsb[tid];
    for (int c = 0; c < 34; ++c) s += il[c]*clsW[c*7 + tid];
    out[b*7 + tid] = s;
  }
}

// ---------------- finalize scalars ----------------------------------------------
__global__ void k_fin(const float* __restrict__ scal, float* __restrict__ out){
  if (threadIdx.x == 0){
    out[10496] = 2.f*scal[0]/(float)(256*196*768);
    out[10497] = scal[1]*(1.f/256.f);
  }
}

extern "C" void kernel_launch(void* const* d_in, const int* in_sizes, int n_in,
                              void* d_out, int out_size, void* d_ws, size_t ws_size,
                              hipStream_t stream) {
  (void)in_sizes; (void)n_in; (void)out_size; (void)ws_size;
  const float* x    = (const float*)d_in[0];
  const float* vqcb = (const float*)d_in[1];
  const float* agcb = (const float*)d_in[2];
  const float* W1   = (const float*)d_in[3];
  const float* b1   = (const float*)d_in[4];
  const float* W2   = (const float*)d_in[5];
  const float* b2   = (const float*)d_in[6];
  const float* gam  = (const float*)d_in[7];
  const float* bet  = (const float*)d_in[8];
  const float* Wp   = (const float*)d_in[9];
  const float* ce   = (const float*)d_in[10];
  const float* clsW = (const float*)d_in[11];
  const float* clsb = (const float*)d_in[12];
  const float* lgs  = (const float*)d_in[13];
  float* out = (float*)d_out;
  char* w = (char*)d_ws;

  float* scal  = (float*)w;
  float* G     = (float*)(w + 256);
  hbf*   aggbf = (hbf*)(w + 39338240ULL);
  hbf*   W1t   = (hbf*)(w + 42090752ULL);
  hbf*   W2t   = (hbf*)(w + 46809344ULL);
  hbf*   Wpt   = (hbf*)(w + 51527936ULL);
  hbf*   h1    = (hbf*)(w + 256);
  float* hbuf  = (float*)(w + 256 + 16777216ULL);
  hbf*   hn    = (hbf*)(w + 256 + 25165824ULL);
  float* tok   = (float*)(w + 256 + 29360128ULL);

  k_init<<<dim3(1), dim3(64), 0, stream>>>(scal);
  k_dg<<<dim3(256), dim3(512), 0, stream>>>(x, vqcb, agcb, aggbf, scal, G);
  const int EIG_SMEM = 39640*4; // 158,560 B
  hipFuncSetAttribute((const void*)k_eigen, hipFuncAttributeMaxDynamicSharedMemorySize, EIG_SMEM);
  k_eigen<<<dim3(256), dim3(1024), EIG_SMEM, stream>>>(G, scal);
  k_tr<<<dim3(96,24), dim3(256), 0, stream>>>(W1, W1t, 768, 3072);
  k_tr<<<dim3(24,96), dim3(256), 0, stream>>>(W2, W2t, 3072, 768);
  k_tr<<<dim3(16,24), dim3(256), 0, stream>>>(Wp, Wpt, 768, 512);
  k_gemm128<1><<<dim3(24,14), dim3(512), 0, stream>>>(aggbf, W1t, b1, (void*)h1, 3072, 768);
  k_gemm<2><<<dim3(12,28), dim3(256), 0, stream>>>(h1, W2t, b2, (void*)hbuf, 1792, 768, 3072);
  k_ln<<<dim3(448), dim3(256), 0, stream>>>(hbuf, gam, bet, hn);
  k_gemm<3><<<dim3(8,28), dim3(256), 0, stream>>>(hn, Wpt, nullptr, (void*)tok, 1792, 512, 768);
  k_head<<<dim3(256), dim3(256), 0, stream>>>(tok, ce, clsW, clsb, lgs, out);
  k_fin<<<dim3(1), dim3(64), 0, stream>>>(scal, out);
}